// Round 12
// baseline (85.813 us; speedup 1.0000x reference)
//
#include <hip/hip_runtime.h>

#define NB 128
#define NL 2048
#define NH 256
#define NSEG 16
#define SEGLEN (NL / NSEG)   // 128
#define RCHUNK 32            // timesteps per reduce-chunk in pass3
#define PB2PITCH 9           // uint2 per channel row (odd*8B -> spread banks)
#define PLANE (NB * NL)      // floats per x-plane
#define CHUNK 32             // fallback kernel chunking
#define NCHUNK (NL / CHUNK)
#define WORDS (CHUNK * 3)

typedef float f32x2 __attribute__((ext_vector_type(2)));
typedef __fp16 f16x2 __attribute__((ext_vector_type(2)));

__device__ __forceinline__ float fexp2(float v) { return __builtin_amdgcn_exp2f(v); }
__device__ __forceinline__ float frcp(float v)  { return __builtin_amdgcn_rcpf(v); }

__device__ __forceinline__ f32x2 pkfma(f32x2 a, f32x2 b, f32x2 c) {
#if __has_builtin(__builtin_elementwise_fma)
    return __builtin_elementwise_fma(a, b, c);
#else
    f32x2 r; r.x = fmaf(a.x, b.x, c.x); r.y = fmaf(a.y, b.y, c.y); return r;
#endif
}
__device__ __forceinline__ f32x2 splat2(float v) { f32x2 r; r.x = v; r.y = v; return r; }

union U32H2 { unsigned int u; f16x2 h; };

// ---------------------------------------------------------------------------
// Transpose x (B,L,3) -> 3 planes xT[c][b*L+t]: 2-timestep pairs adjacent.
// ---------------------------------------------------------------------------
__global__ __launch_bounds__(256) void transpose_x(
        const float* __restrict__ x, float* __restrict__ xT) {
    const int gid = blockIdx.x * 256 + threadIdx.x;   // one per 4 timesteps
    const float4* x4 = (const float4*)x;
    const float4 v0 = x4[gid * 3 + 0];   // t0x t0y t0z t1x
    const float4 v1 = x4[gid * 3 + 1];   // t1y t1z t2x t2y
    const float4 v2 = x4[gid * 3 + 2];   // t2z t3x t3y t3z
    const float4 p0 = {v0.x, v0.w, v1.z, v2.y};
    const float4 p1 = {v0.y, v1.x, v1.w, v2.z};
    const float4 p2 = {v0.z, v1.y, v2.x, v2.w};
    ((float4*)(xT + 0 * PLANE))[gid] = p0;
    ((float4*)(xT + 1 * PLANE))[gid] = p1;
    ((float4*)(xT + 2 * PLANE))[gid] = p2;
}

// ---------------------------------------------------------------------------
// Fold K=3 projection through Wz/Wh, pre-scaled by exp2 constants.
// ---------------------------------------------------------------------------
__global__ __launch_bounds__(256) void fold_kernel(
        const float* __restrict__ Wp, const float* __restrict__ bp,
        const float* __restrict__ Wz, const float* __restrict__ bz,
        const float* __restrict__ Wh, const float* __restrict__ bh,
        float* __restrict__ wsW) {
    const int tid = threadIdx.x;
    const int jj = tid & 15;
    const int hs = tid >> 4;                 // 0..15
    const int j = blockIdx.x * 16 + jj;
    float mz0 = 0.f, mz1 = 0.f, mz2 = 0.f, cz = 0.f;
    float mh0 = 0.f, mh1 = 0.f, mh2 = 0.f, ch = 0.f;
#pragma unroll
    for (int i = 0; i < 16; ++i) {
        const int h = hs * 16 + i;
        const float wz = Wz[h * NH + j];
        const float wh = Wh[h * NH + j];
        const float p0 = Wp[h];
        const float p1 = Wp[NH + h];
        const float p2 = Wp[2 * NH + h];
        const float bb = bp[h];
        mz0 = fmaf(p0, wz, mz0); mz1 = fmaf(p1, wz, mz1); mz2 = fmaf(p2, wz, mz2);
        cz  = fmaf(bb, wz, cz);
        mh0 = fmaf(p0, wh, mh0); mh1 = fmaf(p1, wh, mh1); mh2 = fmaf(p2, wh, mh2);
        ch  = fmaf(bb, wh, ch);
    }
    __shared__ float red[256][9];
    red[tid][0] = mz0; red[tid][1] = mz1; red[tid][2] = mz2; red[tid][3] = cz;
    red[tid][4] = mh0; red[tid][5] = mh1; red[tid][6] = mh2; red[tid][7] = ch;
    __syncthreads();
    if (tid < 16) {
        float v[8];
#pragma unroll
        for (int k = 0; k < 8; ++k) {
            float a = 0.f;
#pragma unroll
            for (int g = 0; g < 16; ++g) a += red[g * 16 + tid][k];
            v[k] = a;
        }
        v[3] += bz[j];
        v[7] += bh[j];
        const float SZ = -1.4426950408889634f;   // -log2(e)
        const float SH = -2.8853900817779268f;   // -2*log2(e)
        float4* w4 = (float4*)(wsW + j * 8);
        w4[0] = make_float4(v[0] * SZ, v[1] * SZ, v[2] * SZ, v[3] * SZ);
        w4[1] = make_float4(v[4] * SH, v[5] * SH, v[6] * SH, v[7] * SH);
    }
}

// Gate math for 2 timesteps, paired rcp (3 trans / 2t):
//   q = e1*(1+e2) = fma(e1,e2,e1);  den = q + e2 + 1 = (1+e1)(1+e2)
//   rp = rcp(den.x*den.y);  rr = {den.y*rp, den.x*rp}
//   AV = q*rr (= 1-z);  B-side handled by caller-specific tail.
#define GATE2_CORE(XQ, U0)                                                      \
        const float* xf_ = (const float*)(XQ);                                  \
        const f32x2 xx_ = *(const f32x2*)&xf_[2*(U0)];                          \
        const f32x2 xy_ = *(const f32x2*)&xf_[8 + 2*(U0)];                      \
        const f32x2 xz_ = *(const f32x2*)&xf_[16 + 2*(U0)];                     \
        const f32x2 s1_ = pkfma(xx_, wax, pkfma(xy_, way, pkfma(xz_, waz, waw)));\
        const f32x2 s2_ = pkfma(xx_, wbx, pkfma(xy_, wby, pkfma(xz_, wbz, wbw)));\
        f32x2 e1_, e2_;                                                         \
        e1_.x = fexp2(s1_.x); e1_.y = fexp2(s1_.y);                             \
        e2_.x = fexp2(s2_.x); e2_.y = fexp2(s2_.y);                             \
        const f32x2 q_ = pkfma(e1_, e2_, e1_);                                  \
        f32x2 den_ = q_ + e2_;                                                  \
        den_ = den_ + 1.f;                                                      \
        const float rp_ = frcp(den_.x * den_.y);                                \
        f32x2 rr_; rr_.x = den_.y * rp_; rr_.y = den_.x * rp_;

// Load 8 timesteps (sub-chunk SC) from the 3 plane pointers.
#define LOAD8(XQ, SC)                                                           \
    {                                                                           \
        XQ[0] = p04[(SC) * 2];     XQ[1] = p04[(SC) * 2 + 1];                   \
        XQ[2] = p14[(SC) * 2];     XQ[3] = p14[(SC) * 2 + 1];                   \
        XQ[4] = p24[(SC) * 2];     XQ[5] = p24[(SC) * 2 + 1];                   \
    }

// ---------------------------------------------------------------------------
// Pass 1: per-(batch, segment) blocks (thread = channel). Segment composite
// (A, B): h_end = A*h_start + B. Segment 15's composite is never read -> skip.
// ---------------------------------------------------------------------------
__global__ __launch_bounds__(256, 8) void pass1_seg(
        const float* __restrict__ xT, const float* __restrict__ wsW,
        float* __restrict__ Aarr, float* __restrict__ Barr) {
    const int tid = threadIdx.x;
    const int b = blockIdx.x >> 4;           // NSEG = 16
    const int s = blockIdx.x & (NSEG - 1);
    if (s == NSEG - 1) return;               // last segment's composite unused

    const float4* wv = (const float4*)(wsW + tid * 8);
    const float4 wA4 = wv[0];
    const float4 wB4 = wv[1];
    const f32x2 wax = splat2(wA4.x), way = splat2(wA4.y), waz = splat2(wA4.z), waw = splat2(wA4.w);
    const f32x2 wbx = splat2(wB4.x), wby = splat2(wB4.y), wbz = splat2(wB4.z), wbw = splat2(wB4.w);

    const int base = b * NL + s * SEGLEN;    // block-uniform
    const float4* p04 = (const float4*)(xT + 0 * PLANE + base);
    const float4* p14 = (const float4*)(xT + 1 * PLANE + base);
    const float4* p24 = (const float4*)(xT + 2 * PLANE + base);

#define P1_BODY(XQ)                                                             \
    _Pragma("unroll")                                                           \
    for (int u0 = 0; u0 < 4; ++u0) {                                            \
        GATE2_CORE(XQ, u0);                                                     \
        const f32x2 av = q_ * rr_;            /* a = 1-z    */                  \
        const f32x2 bv = (1.f - e2_) * rr_;   /* b = z*tanh */                  \
        Bacc = fmaf(av.x, Bacc, bv.x);                                          \
        Bacc = fmaf(av.y, Bacc, bv.y);                                          \
        Apk *= av;                                                              \
    }

    f32x2 Apk = { 1.f, 1.f };
    float Bacc = 0.f;
    float4 xa[6], xb[6];
    LOAD8(xa, 0);
    for (int c = 0; c < 8; ++c) {            // 16 timesteps per iter
        LOAD8(xb, 2 * c + 1);
        P1_BODY(xa);
        const int nxt = (c < 7) ? (2 * c + 2) : 0;
        LOAD8(xa, nxt);
        P1_BODY(xb);
    }
    const size_t o = ((size_t)b * NSEG + s) * NH + tid;
    Aarr[o] = Apk.x * Apk.y;
    Barr[o] = Bacc;
#undef P1_BODY
}

// ---------------------------------------------------------------------------
// Pass 3: per-(batch, segment) blocks. Prefix over earlier segments' (A,B),
// then scaled recurrence g = a*g + bw where bw = wg*z*tanh is produced
// directly by the gate tail (wg folded in). Pred-reduction via b64-packed
// LDS transpose: stage1 8x ds_write_b64, stage2 128 thr x 16 ds_read_b64.
// ---------------------------------------------------------------------------
__global__ __launch_bounds__(256, 8) void pass3_pred(
        const float* __restrict__ xT, const float* __restrict__ wsW,
        const float* __restrict__ Wg, const float* __restrict__ bg,
        const float* __restrict__ Aarr, const float* __restrict__ Barr,
        float* __restrict__ out) {
    const int tid = threadIdx.x;
    const int b = blockIdx.x >> 4;
    const int s = blockIdx.x & (NSEG - 1);

    const float4* wv = (const float4*)(wsW + tid * 8);
    const float4 wA4 = wv[0];
    const float4 wB4 = wv[1];
    const f32x2 wax = splat2(wA4.x), way = splat2(wA4.y), waz = splat2(wA4.z), waw = splat2(wA4.w);
    const f32x2 wbx = splat2(wB4.x), wby = splat2(wB4.y), wbz = splat2(wB4.z), wbw = splat2(wB4.w);
    const float wg = Wg[tid];
    const f32x2 wgpk = splat2(wg);
    const f32x2 mwgpk = splat2(-wg);
    const float bgv = bg[0];

    // ---- segment-start state: prefix over earlier segments' (A,B) ----
    float h = 0.f;
    {
        const size_t pbase = (size_t)b * NSEG * NH + tid;
        for (int k0 = 0; k0 < s; k0 += 8) {      // s uniform per block
            float Ak[8], Bk[8];
#pragma unroll
            for (int k = 0; k < 8; ++k) {
                const int kk = k0 + k;
                const bool u = kk < s;           // uniform predicate
                Ak[k] = u ? Aarr[pbase + (size_t)kk * NH] : 1.f;
                Bk[k] = u ? Barr[pbase + (size_t)kk * NH] : 0.f;
            }
#pragma unroll
            for (int k = 0; k < 8; ++k) h = fmaf(Ak[k], h, Bk[k]);
        }
    }
    float g = h * wg;                        // scaled state: pred_t = g_{t-1}

    const int base = b * NL + s * SEGLEN;
    const float4* p04 = (const float4*)(xT + 0 * PLANE + base);
    const float4* p14 = (const float4*)(xT + 1 * PLANE + base);
    const float4* p24 = (const float4*)(xT + 2 * PLANE + base);

    __shared__ uint2 pbuf2[NH * PB2PITCH];    // f16x2 t-pair pairs, 18432 B
    __shared__ uint2 part2[16 * PB2PITCH];    // [grp][qh] two t-pairs

    const int qh   = tid & 7;                // stage2: t-quad index (0..7)
    const int grp  = tid >> 3;               // stage2: channel group (16 ch)

#define P3_BODY(XQ, Q0)                                                         \
    _Pragma("unroll")                                                           \
    for (int u0 = 0; u0 < 4; ++u0) {                                            \
        GATE2_CORE(XQ, u0);                                                     \
        const f32x2 av = q_ * rr_;                                              \
        const f32x2 bw = pkfma(e2_, mwgpk, wgpk) * rr_;  /* wg*z*tanh */        \
        const float p0_ = g;                 /* pred uses state BEFORE update */\
        g = fmaf(av.x, g, bw.x);                                                \
        const float p1_ = g;                                                    \
        g = fmaf(av.y, g, bw.y);                                                \
        U32H2 pk_; pk_.h = __builtin_amdgcn_cvt_pkrtz(p0_, p1_);                \
        pk[(Q0) + u0] = pk_.u;                                                  \
    }

    float4 xa[6], xb[6];
    unsigned int pk[16];
    LOAD8(xa, 0);
    for (int c2 = 0; c2 < 4; ++c2) {         // 32 timesteps per iter
        LOAD8(xb, 4 * c2 + 1);
        P3_BODY(xa, 0);
        LOAD8(xa, 4 * c2 + 2);
        P3_BODY(xb, 4);
        LOAD8(xb, 4 * c2 + 3);
        P3_BODY(xa, 8);
        {
            const int nxt = (c2 < 3) ? (4 * c2 + 4) : 0;
            LOAD8(xa, nxt);
        }
        P3_BODY(xb, 12);
        // stage 1: 8 b64 writes (uint2), ~2 lanes/bank per phase
#pragma unroll
        for (int v = 0; v < 8; ++v)
            pbuf2[tid * PB2PITCH + v] = make_uint2(pk[2 * v], pk[2 * v + 1]);
        __syncthreads();
        // stage 2: 128 threads; (grp,qh) sums 16 channels for t-pairs
        // {2qh, 2qh+1}; channel order rotated by grp to spread banks.
        if (tid < 128) {
            f16x2 aLo = (f16x2)0.f, aHi = (f16x2)0.f;
#pragma unroll
            for (int jj = 0; jj < 16; ++jj) {
                const int j = (jj + grp) & 15;
                const uint2 rd = pbuf2[(grp * 16 + j) * PB2PITCH + qh];
                U32H2 lo; lo.u = rd.x;
                U32H2 hi; hi.u = rd.y;
                aLo += lo.h;
                aHi += hi.h;
            }
            U32H2 wLo; wLo.h = aLo;
            U32H2 wHi; wHi.h = aHi;
            part2[grp * PB2PITCH + qh] = make_uint2(wLo.u, wHi.u);
        }
        __syncthreads();
        // stage 3: 16 threads; t-pair tid = dword tid of each grp row
        if (tid < 16) {
            const unsigned int* p2u = (const unsigned int*)part2;
            f16x2 a3 = (f16x2)0.f;
#pragma unroll
            for (int g2 = 0; g2 < 16; ++g2) {
                U32H2 rd; rd.u = p2u[g2 * (2 * PB2PITCH) + tid];
                a3 += rd.h;
            }
            float2 o2;
            o2.x = (float)a3.x + bgv;
            o2.y = (float)a3.y + bgv;
            *(float2*)&out[(size_t)b * NL + (size_t)s * SEGLEN + c2 * RCHUNK + 2 * tid] = o2;
        }
    }
#undef P3_BODY
}

// ---------------------------------------------------------------------------
// Fallback (ws too small): monolithic scan, 128 blocks x 256 thr (orig x).
// ---------------------------------------------------------------------------
__global__ __launch_bounds__(256) void scan_kernel_nows(
        const float* __restrict__ x, const float* __restrict__ wsW,
        const float* __restrict__ Wg, const float* __restrict__ bg,
        float* __restrict__ out) {
    const int tid  = threadIdx.x;
    const int lane = tid & 63;
    const int wid  = tid >> 6;
    const int b = blockIdx.x;

    const float4* wv = (const float4*)(wsW + tid * 8);
    const float4 wA = wv[0];
    const float4 wB = wv[1];
    const float  wg = Wg[tid];
    const float  bgv = bg[0];

    const float* xb = x + (size_t)b * (NL * 3);

    __shared__ float4 xbuf[2][CHUNK];
    __shared__ float  predbuf[2][4][CHUNK];
    float* xbf = (float*)xbuf;

    const int sw = tid;
    const int sidx = (sw / 3) * 4 + (sw % 3);

    if (tid < WORDS) xbf[sidx] = xb[sw];
    __syncthreads();

    float h = 0.f;
    for (int c = 0; c < NCHUNK; ++c) {
        const int cur = c & 1;
        float nv = 0.f;
        if (tid < WORDS && c + 1 < NCHUNK) nv = xb[(c + 1) * WORDS + sw];

        float p[CHUNK];
        const float4* xc = xbuf[cur];
#pragma unroll
        for (int t = 0; t < CHUNK; ++t) {
            const float4 xv = xc[t];
            const float e1 = fexp2(fmaf(xv.x, wA.x, fmaf(xv.y, wA.y, fmaf(xv.z, wA.z, wA.w))));
            const float e2 = fexp2(fmaf(xv.x, wB.x, fmaf(xv.y, wB.y, fmaf(xv.z, wB.z, wB.w))));
            const float d2 = 1.f + e2;
            const float e1d2 = e1 * d2;
            const float r  = frcp(e1d2 + d2);
            p[t] = h * wg;
            h = fmaf(e1d2 * r, h, (1.f - e2) * r);
        }
#pragma unroll
        for (int t = 0; t < CHUNK; ++t) {
            float v = p[t];
            v += __shfl_xor(v, 1, 64);
            v += __shfl_xor(v, 2, 64);
            v += __shfl_xor(v, 4, 64);
            v += __shfl_xor(v, 8, 64);
            v += __shfl_xor(v, 16, 64);
            v += __shfl_xor(v, 32, 64);
            p[t] = v;
        }
        if (lane == 0) {
            float4* dpr = (float4*)&predbuf[cur][wid][0];
#pragma unroll
            for (int j2 = 0; j2 < CHUNK / 4; ++j2)
                dpr[j2] = make_float4(p[4*j2], p[4*j2+1], p[4*j2+2], p[4*j2+3]);
        }
        if (tid < WORDS && c + 1 < NCHUNK) xbf[(cur ^ 1) * CHUNK * 4 + sidx] = nv;
        __syncthreads();
        if (tid < CHUNK) {
            const float ssum = predbuf[cur][0][tid] + predbuf[cur][1][tid]
                             + predbuf[cur][2][tid] + predbuf[cur][3][tid];
            out[(size_t)b * NL + c * CHUNK + tid] = ssum + bgv;
        }
    }
}

extern "C" void kernel_launch(void* const* d_in, const int* in_sizes, int n_in,
                              void* d_out, int out_size, void* d_ws, size_t ws_size,
                              hipStream_t stream) {
    const float* x  = (const float*)d_in[0];
    const float* Wp = (const float*)d_in[1];
    const float* bp = (const float*)d_in[2];
    const float* Wz = (const float*)d_in[3];
    const float* bz = (const float*)d_in[4];
    const float* Wh = (const float*)d_in[5];
    const float* bh = (const float*)d_in[6];
    const float* Wg = (const float*)d_in[7];
    const float* bg = (const float*)d_in[8];
    float* out = (float*)d_out;

    float* wsW = (float*)d_ws;                       // 8 KB folded weights
    float* Aarr = wsW + 8 * NH;                      // 2 MB
    float* Barr = Aarr + (size_t)NB * NSEG * NH;     // 2 MB
    float* xTp  = Barr + (size_t)NB * NSEG * NH;     // 3 MB planes

    const size_t need = ((size_t)(8 * NH) + 2 * (size_t)NB * NSEG * NH
                        + 3 * (size_t)PLANE) * sizeof(float);

    fold_kernel<<<16, 256, 0, stream>>>(Wp, bp, Wz, bz, Wh, bh, wsW);

    if (ws_size >= need) {
        transpose_x<<<PLANE / 4 / 256, 256, 0, stream>>>(x, xTp);
        pass1_seg<<<NB * NSEG, 256, 0, stream>>>(xTp, wsW, Aarr, Barr);
        pass3_pred<<<NB * NSEG, 256, 0, stream>>>(xTp, wsW, Wg, bg, Aarr, Barr, out);
    } else {
        scan_kernel_nows<<<NB, 256, 0, stream>>>(x, wsW, Wg, bg, out);
    }
}

// Round 14
// 75.730 us; speedup vs baseline: 1.1331x; 1.1331x over previous
//
#include <hip/hip_runtime.h>

#define NB 128
#define NL 2048
#define NH 256
#define NSEG 16
#define SEGLEN (NL / NSEG)   // 128
#define RCHUNK 32            // timesteps per reduce-chunk in pass3
#define PBPITCH 17           // uints per channel row in pbuf (odd -> 2-way banks)
#define PLANE (NB * NL)      // floats per x-plane
#define CHUNK 32             // fallback kernel chunking
#define NCHUNK (NL / CHUNK)
#define WORDS (CHUNK * 3)

typedef float f32x2 __attribute__((ext_vector_type(2)));
typedef __fp16 f16x2 __attribute__((ext_vector_type(2)));

__device__ __forceinline__ float fexp2(float v) { return __builtin_amdgcn_exp2f(v); }
__device__ __forceinline__ float frcp(float v)  { return __builtin_amdgcn_rcpf(v); }

__device__ __forceinline__ f32x2 pkfma(f32x2 a, f32x2 b, f32x2 c) {
#if __has_builtin(__builtin_elementwise_fma)
    return __builtin_elementwise_fma(a, b, c);
#else
    f32x2 r; r.x = fmaf(a.x, b.x, c.x); r.y = fmaf(a.y, b.y, c.y); return r;
#endif
}
__device__ __forceinline__ f32x2 splat2(float v) { f32x2 r; r.x = v; r.y = v; return r; }

union U32H2 { unsigned int u; f16x2 h; };

// ---------------------------------------------------------------------------
// Transpose x (B,L,3) -> 3 planes xT[c][b*L+t]: 2-timestep pairs adjacent.
// ---------------------------------------------------------------------------
__global__ __launch_bounds__(256) void transpose_x(
        const float* __restrict__ x, float* __restrict__ xT) {
    const int gid = blockIdx.x * 256 + threadIdx.x;   // one per 4 timesteps
    const float4* x4 = (const float4*)x;
    const float4 v0 = x4[gid * 3 + 0];   // t0x t0y t0z t1x
    const float4 v1 = x4[gid * 3 + 1];   // t1y t1z t2x t2y
    const float4 v2 = x4[gid * 3 + 2];   // t2z t3x t3y t3z
    const float4 p0 = {v0.x, v0.w, v1.z, v2.y};
    const float4 p1 = {v0.y, v1.x, v1.w, v2.z};
    const float4 p2 = {v0.z, v1.y, v2.x, v2.w};
    ((float4*)(xT + 0 * PLANE))[gid] = p0;
    ((float4*)(xT + 1 * PLANE))[gid] = p1;
    ((float4*)(xT + 2 * PLANE))[gid] = p2;
}

// ---------------------------------------------------------------------------
// Fold K=3 projection through Wz/Wh, pre-scaled by exp2 constants.
// ---------------------------------------------------------------------------
__global__ __launch_bounds__(256) void fold_kernel(
        const float* __restrict__ Wp, const float* __restrict__ bp,
        const float* __restrict__ Wz, const float* __restrict__ bz,
        const float* __restrict__ Wh, const float* __restrict__ bh,
        float* __restrict__ wsW) {
    const int tid = threadIdx.x;
    const int jj = tid & 15;
    const int hs = tid >> 4;                 // 0..15
    const int j = blockIdx.x * 16 + jj;
    float mz0 = 0.f, mz1 = 0.f, mz2 = 0.f, cz = 0.f;
    float mh0 = 0.f, mh1 = 0.f, mh2 = 0.f, ch = 0.f;
#pragma unroll
    for (int i = 0; i < 16; ++i) {
        const int h = hs * 16 + i;
        const float wz = Wz[h * NH + j];
        const float wh = Wh[h * NH + j];
        const float p0 = Wp[h];
        const float p1 = Wp[NH + h];
        const float p2 = Wp[2 * NH + h];
        const float bb = bp[h];
        mz0 = fmaf(p0, wz, mz0); mz1 = fmaf(p1, wz, mz1); mz2 = fmaf(p2, wz, mz2);
        cz  = fmaf(bb, wz, cz);
        mh0 = fmaf(p0, wh, mh0); mh1 = fmaf(p1, wh, mh1); mh2 = fmaf(p2, wh, mh2);
        ch  = fmaf(bb, wh, ch);
    }
    __shared__ float red[256][9];
    red[tid][0] = mz0; red[tid][1] = mz1; red[tid][2] = mz2; red[tid][3] = cz;
    red[tid][4] = mh0; red[tid][5] = mh1; red[tid][6] = mh2; red[tid][7] = ch;
    __syncthreads();
    if (tid < 16) {
        float v[8];
#pragma unroll
        for (int k = 0; k < 8; ++k) {
            float a = 0.f;
#pragma unroll
            for (int g = 0; g < 16; ++g) a += red[g * 16 + tid][k];
            v[k] = a;
        }
        v[3] += bz[j];
        v[7] += bh[j];
        const float SZ = -1.4426950408889634f;   // -log2(e)
        const float SH = -2.8853900817779268f;   // -2*log2(e)
        float4* w4 = (float4*)(wsW + j * 8);
        w4[0] = make_float4(v[0] * SZ, v[1] * SZ, v[2] * SZ, v[3] * SZ);
        w4[1] = make_float4(v[4] * SH, v[5] * SH, v[6] * SH, v[7] * SH);
    }
}

// Gate math for 2 timesteps, 12 VALU + 6 trans:
//   q  = e1*(1+e2) = fma(e1,e2,e1)
//   den = (1+e1)(1+e2) = q + e2 + 1
//   a = q/den, b = (1-e2)/den  (two direct rcps; trans pipe has slack)
#define GATE2(XQ, U0, AV, BV)                                                   \
    {                                                                           \
        const float* xf_ = (const float*)(XQ);                                  \
        const f32x2 xx_ = *(const f32x2*)&xf_[2*(U0)];                          \
        const f32x2 xy_ = *(const f32x2*)&xf_[8 + 2*(U0)];                      \
        const f32x2 xz_ = *(const f32x2*)&xf_[16 + 2*(U0)];                     \
        const f32x2 s1_ = pkfma(xx_, wax, pkfma(xy_, way, pkfma(xz_, waz, waw)));\
        const f32x2 s2_ = pkfma(xx_, wbx, pkfma(xy_, wby, pkfma(xz_, wbz, wbw)));\
        f32x2 e1_, e2_;                                                         \
        e1_.x = fexp2(s1_.x); e1_.y = fexp2(s1_.y);                             \
        e2_.x = fexp2(s2_.x); e2_.y = fexp2(s2_.y);                             \
        const f32x2 q_  = pkfma(e1_, e2_, e1_);                                 \
        f32x2 den_ = q_ + e2_;                                                  \
        den_ = den_ + 1.f;                                                      \
        f32x2 rr_; rr_.x = frcp(den_.x); rr_.y = frcp(den_.y);                  \
        AV = q_ * rr_;                     /* a = 1-z    */                     \
        BV = (1.f - e2_) * rr_;            /* b = z*tanh */                     \
    }

// Load 8 timesteps (sub-chunk SC) from the 3 plane pointers.
#define LOAD8(XQ, SC)                                                           \
    {                                                                           \
        XQ[0] = p04[(SC) * 2];     XQ[1] = p04[(SC) * 2 + 1];                   \
        XQ[2] = p14[(SC) * 2];     XQ[3] = p14[(SC) * 2 + 1];                   \
        XQ[4] = p24[(SC) * 2];     XQ[5] = p24[(SC) * 2 + 1];                   \
    }

// ---------------------------------------------------------------------------
// Pass 1: per-(batch, segment) blocks (thread = channel). Segment composite
// (A, B): h_end = A*h_start + B. Segment 15's composite is never read -> skip.
// ---------------------------------------------------------------------------
__global__ __launch_bounds__(256, 8) void pass1_seg(
        const float* __restrict__ xT, const float* __restrict__ wsW,
        float* __restrict__ Aarr, float* __restrict__ Barr) {
    const int tid = threadIdx.x;
    const int b = blockIdx.x >> 4;           // NSEG = 16
    const int s = blockIdx.x & (NSEG - 1);
    if (s == NSEG - 1) return;               // last segment's composite unused

    const float4* wv = (const float4*)(wsW + tid * 8);
    const float4 wA4 = wv[0];
    const float4 wB4 = wv[1];
    const f32x2 wax = splat2(wA4.x), way = splat2(wA4.y), waz = splat2(wA4.z), waw = splat2(wA4.w);
    const f32x2 wbx = splat2(wB4.x), wby = splat2(wB4.y), wbz = splat2(wB4.z), wbw = splat2(wB4.w);

    const int base = b * NL + s * SEGLEN;    // block-uniform
    const float4* p04 = (const float4*)(xT + 0 * PLANE + base);
    const float4* p14 = (const float4*)(xT + 1 * PLANE + base);
    const float4* p24 = (const float4*)(xT + 2 * PLANE + base);

#define P1_BODY(XQ)                                                             \
    _Pragma("unroll")                                                           \
    for (int u0 = 0; u0 < 4; ++u0) {                                            \
        f32x2 av, bv;                                                           \
        GATE2(XQ, u0, av, bv);                                                  \
        Bacc = fmaf(av.x, Bacc, bv.x);                                          \
        Bacc = fmaf(av.y, Bacc, bv.y);                                          \
        Apk *= av;                                                              \
    }

    f32x2 Apk = { 1.f, 1.f };
    float Bacc = 0.f;
    float4 xa[6], xb[6];
    LOAD8(xa, 0);
    for (int c = 0; c < 8; ++c) {            // 16 timesteps per iter
        LOAD8(xb, 2 * c + 1);
        P1_BODY(xa);
        const int nxt = (c < 7) ? (2 * c + 2) : 0;
        LOAD8(xa, nxt);
        P1_BODY(xb);
    }
    const size_t o = ((size_t)b * NSEG + s) * NH + tid;
    Aarr[o] = Apk.x * Apk.y;
    Barr[o] = Bacc;
#undef P1_BODY
}

// ---------------------------------------------------------------------------
// Pass 3: per-(batch, segment) blocks. Prefix over earlier segments' (A,B)
// (loop bounded by s, uniform), then scaled recurrence g = a*g + wg*b.
// Pred-reduction over 256 channels via f16x2-packed LDS transpose per 32 t.
// ---------------------------------------------------------------------------
__global__ __launch_bounds__(256, 8) void pass3_pred(
        const float* __restrict__ xT, const float* __restrict__ wsW,
        const float* __restrict__ Wg, const float* __restrict__ bg,
        const float* __restrict__ Aarr, const float* __restrict__ Barr,
        float* __restrict__ out) {
    const int tid = threadIdx.x;
    const int b = blockIdx.x >> 4;
    const int s = blockIdx.x & (NSEG - 1);

    const float4* wv = (const float4*)(wsW + tid * 8);
    const float4 wA4 = wv[0];
    const float4 wB4 = wv[1];
    const f32x2 wax = splat2(wA4.x), way = splat2(wA4.y), waz = splat2(wA4.z), waw = splat2(wA4.w);
    const f32x2 wbx = splat2(wB4.x), wby = splat2(wB4.y), wbz = splat2(wB4.z), wbw = splat2(wB4.w);
    const float wg = Wg[tid];
    const f32x2 wgpk = splat2(wg);
    const float bgv = bg[0];

    // ---- segment-start state: prefix over earlier segments' (A,B) ----
    float h = 0.f;
    {
        const size_t pbase = (size_t)b * NSEG * NH + tid;
        for (int k0 = 0; k0 < s; k0 += 8) {      // s uniform per block
            float Ak[8], Bk[8];
#pragma unroll
            for (int k = 0; k < 8; ++k) {
                const int kk = k0 + k;
                const bool u = kk < s;           // uniform predicate
                Ak[k] = u ? Aarr[pbase + (size_t)kk * NH] : 1.f;
                Bk[k] = u ? Barr[pbase + (size_t)kk * NH] : 0.f;
            }
#pragma unroll
            for (int k = 0; k < 8; ++k) h = fmaf(Ak[k], h, Bk[k]);
        }
    }
    float g = h * wg;                        // scaled state: pred_t = g_{t-1}

    const int base = b * NL + s * SEGLEN;
    const float4* p04 = (const float4*)(xT + 0 * PLANE + base);
    const float4* p14 = (const float4*)(xT + 1 * PLANE + base);
    const float4* p24 = (const float4*)(xT + 2 * PLANE + base);

    __shared__ unsigned int pbuf[NH * PBPITCH];   // f16x2 t-pairs, 17408 B
    __shared__ unsigned int part2[16 * PBPITCH];  // [grp][q] f16x2

    const int q   = tid & 15;                // stage2: t-pair index (0..15)
    const int grp = tid >> 4;                // stage2: channel group (16 ch)

#define P3_BODY(XQ, Q0)                                                         \
    _Pragma("unroll")                                                           \
    for (int u0 = 0; u0 < 4; ++u0) {                                            \
        f32x2 av, bv;                                                           \
        GATE2(XQ, u0, av, bv);                                                  \
        const f32x2 bw = bv * wgpk;                                             \
        const float p0_ = g;                 /* pred uses state BEFORE update */\
        g = fmaf(av.x, g, bw.x);                                                \
        const float p1_ = g;                                                    \
        g = fmaf(av.y, g, bw.y);                                                \
        U32H2 pk_; pk_.h = __builtin_amdgcn_cvt_pkrtz(p0_, p1_);                \
        pbuf[tid * PBPITCH + (Q0) + u0] = pk_.u;                                \
    }

    float4 xa[6], xb[6];
    LOAD8(xa, 0);
    for (int c2 = 0; c2 < 4; ++c2) {         // 32 timesteps per iter
        LOAD8(xb, 4 * c2 + 1);
        P3_BODY(xa, 0);
        LOAD8(xa, 4 * c2 + 2);
        P3_BODY(xb, 4);
        LOAD8(xb, 4 * c2 + 3);
        P3_BODY(xa, 8);
        {
            const int nxt = (c2 < 3) ? (4 * c2 + 4) : 0;
            LOAD8(xa, nxt);
        }
        P3_BODY(xb, 12);
        __syncthreads();
        // stage 2: thread (grp,q) sums 16 channels for t-pair q (pk_add_f16)
        {
            f16x2 acc2 = (f16x2)0.f;
#pragma unroll
            for (int j = 0; j < 16; ++j) {
                U32H2 rd; rd.u = pbuf[(grp * 16 + j) * PBPITCH + q];
                acc2 += rd.h;
            }
            U32H2 wr; wr.h = acc2;
            part2[grp * PBPITCH + q] = wr.u;
        }
        __syncthreads();
        // stage 3: 16 threads sum 16 group-partials for their t-pair + bias
        if (tid < 16) {
            f16x2 a3 = (f16x2)0.f;
#pragma unroll
            for (int g2 = 0; g2 < 16; ++g2) {
                U32H2 rd; rd.u = part2[g2 * PBPITCH + tid];
                a3 += rd.h;
            }
            float2 o2;
            o2.x = (float)a3.x + bgv;
            o2.y = (float)a3.y + bgv;
            *(float2*)&out[(size_t)b * NL + (size_t)s * SEGLEN + c2 * RCHUNK + 2 * tid] = o2;
        }
    }
#undef P3_BODY
}

// ---------------------------------------------------------------------------
// Fallback (ws too small): monolithic scan, 128 blocks x 256 thr (orig x).
// ---------------------------------------------------------------------------
__global__ __launch_bounds__(256) void scan_kernel_nows(
        const float* __restrict__ x, const float* __restrict__ wsW,
        const float* __restrict__ Wg, const float* __restrict__ bg,
        float* __restrict__ out) {
    const int tid  = threadIdx.x;
    const int lane = tid & 63;
    const int wid  = tid >> 6;
    const int b = blockIdx.x;

    const float4* wv = (const float4*)(wsW + tid * 8);
    const float4 wA = wv[0];
    const float4 wB = wv[1];
    const float  wg = Wg[tid];
    const float  bgv = bg[0];

    const float* xb = x + (size_t)b * (NL * 3);

    __shared__ float4 xbuf[2][CHUNK];
    __shared__ float  predbuf[2][4][CHUNK];
    float* xbf = (float*)xbuf;

    const int sw = tid;
    const int sidx = (sw / 3) * 4 + (sw % 3);

    if (tid < WORDS) xbf[sidx] = xb[sw];
    __syncthreads();

    float h = 0.f;
    for (int c = 0; c < NCHUNK; ++c) {
        const int cur = c & 1;
        float nv = 0.f;
        if (tid < WORDS && c + 1 < NCHUNK) nv = xb[(c + 1) * WORDS + sw];

        float p[CHUNK];
        const float4* xc = xbuf[cur];
#pragma unroll
        for (int t = 0; t < CHUNK; ++t) {
            const float4 xv = xc[t];
            const float e1 = fexp2(fmaf(xv.x, wA.x, fmaf(xv.y, wA.y, fmaf(xv.z, wA.z, wA.w))));
            const float e2 = fexp2(fmaf(xv.x, wB.x, fmaf(xv.y, wB.y, fmaf(xv.z, wB.z, wB.w))));
            const float d2 = 1.f + e2;
            const float e1d2 = e1 * d2;
            const float r  = frcp(e1d2 + d2);
            p[t] = h * wg;
            h = fmaf(e1d2 * r, h, (1.f - e2) * r);
        }
#pragma unroll
        for (int t = 0; t < CHUNK; ++t) {
            float v = p[t];
            v += __shfl_xor(v, 1, 64);
            v += __shfl_xor(v, 2, 64);
            v += __shfl_xor(v, 4, 64);
            v += __shfl_xor(v, 8, 64);
            v += __shfl_xor(v, 16, 64);
            v += __shfl_xor(v, 32, 64);
            p[t] = v;
        }
        if (lane == 0) {
            float4* dpr = (float4*)&predbuf[cur][wid][0];
#pragma unroll
            for (int j2 = 0; j2 < CHUNK / 4; ++j2)
                dpr[j2] = make_float4(p[4*j2], p[4*j2+1], p[4*j2+2], p[4*j2+3]);
        }
        if (tid < WORDS && c + 1 < NCHUNK) xbf[(cur ^ 1) * CHUNK * 4 + sidx] = nv;
        __syncthreads();
        if (tid < CHUNK) {
            const float ssum = predbuf[cur][0][tid] + predbuf[cur][1][tid]
                             + predbuf[cur][2][tid] + predbuf[cur][3][tid];
            out[(size_t)b * NL + c * CHUNK + tid] = ssum + bgv;
        }
    }
}

extern "C" void kernel_launch(void* const* d_in, const int* in_sizes, int n_in,
                              void* d_out, int out_size, void* d_ws, size_t ws_size,
                              hipStream_t stream) {
    const float* x  = (const float*)d_in[0];
    const float* Wp = (const float*)d_in[1];
    const float* bp = (const float*)d_in[2];
    const float* Wz = (const float*)d_in[3];
    const float* bz = (const float*)d_in[4];
    const float* Wh = (const float*)d_in[5];
    const float* bh = (const float*)d_in[6];
    const float* Wg = (const float*)d_in[7];
    const float* bg = (const float*)d_in[8];
    float* out = (float*)d_out;

    float* wsW = (float*)d_ws;                       // 8 KB folded weights
    float* Aarr = wsW + 8 * NH;                      // 2 MB
    float* Barr = Aarr + (size_t)NB * NSEG * NH;     // 2 MB
    float* xTp  = Barr + (size_t)NB * NSEG * NH;     // 3 MB planes

    const size_t need = ((size_t)(8 * NH) + 2 * (size_t)NB * NSEG * NH
                        + 3 * (size_t)PLANE) * sizeof(float);

    fold_kernel<<<16, 256, 0, stream>>>(Wp, bp, Wz, bz, Wh, bh, wsW);

    if (ws_size >= need) {
        transpose_x<<<PLANE / 4 / 256, 256, 0, stream>>>(x, xTp);
        pass1_seg<<<NB * NSEG, 256, 0, stream>>>(xTp, wsW, Aarr, Barr);
        pass3_pred<<<NB * NSEG, 256, 0, stream>>>(xTp, wsW, Wg, bg, Aarr, Barr, out);
    } else {
        scan_kernel_nows<<<NB, 256, 0, stream>>>(x, wsW, Wg, bg, out);
    }
}

// Round 16
// 73.429 us; speedup vs baseline: 1.1687x; 1.0313x over previous
//
#include <hip/hip_runtime.h>

#define NB 128
#define NL 2048
#define NH 256
#define NSEG 16
#define SEGLEN (NL / NSEG)   // 128
#define RCHUNK 32            // timesteps per reduce-chunk in pass3
#define PBPITCH 17           // uints per channel row in pbuf (odd -> 2-way banks)
#define PLANE (NB * NL)      // floats per x-plane
#define CHUNK 32             // fallback kernel chunking
#define NCHUNK (NL / CHUNK)
#define WORDS (CHUNK * 3)

typedef float f32x2 __attribute__((ext_vector_type(2)));
typedef __fp16 f16x2 __attribute__((ext_vector_type(2)));

__device__ __forceinline__ float fexp2(float v) { return __builtin_amdgcn_exp2f(v); }
__device__ __forceinline__ float frcp(float v)  { return __builtin_amdgcn_rcpf(v); }

__device__ __forceinline__ f32x2 pkfma(f32x2 a, f32x2 b, f32x2 c) {
#if __has_builtin(__builtin_elementwise_fma)
    return __builtin_elementwise_fma(a, b, c);
#else
    f32x2 r; r.x = fmaf(a.x, b.x, c.x); r.y = fmaf(a.y, b.y, c.y); return r;
#endif
}
__device__ __forceinline__ f32x2 splat2(float v) { f32x2 r; r.x = v; r.y = v; return r; }

union U32H2 { unsigned int u; f16x2 h; };

// ---------------------------------------------------------------------------
// Merged prep kernel: blocks 0-15 fold the K=3 projection through Wz/Wh
// (pre-scaled by exp2 constants); blocks 16.. transpose x into 3 planes
// xT[c][b*L+t] (2-timestep pairs adjacent). One launch instead of two —
// fold's latency-bound tail hides under the transpose's memory traffic.
// ---------------------------------------------------------------------------
__global__ __launch_bounds__(256) void prep_kernel(
        const float* __restrict__ x, float* __restrict__ xT,
        const float* __restrict__ Wp, const float* __restrict__ bp,
        const float* __restrict__ Wz, const float* __restrict__ bz,
        const float* __restrict__ Wh, const float* __restrict__ bh,
        float* __restrict__ wsW) {
    const int tid = threadIdx.x;
    if (blockIdx.x >= 16) {
        // ---- transpose part ----
        const int gid = (blockIdx.x - 16) * 256 + tid;   // one per 4 timesteps
        const float4* x4 = (const float4*)x;
        const float4 v0 = x4[gid * 3 + 0];   // t0x t0y t0z t1x
        const float4 v1 = x4[gid * 3 + 1];   // t1y t1z t2x t2y
        const float4 v2 = x4[gid * 3 + 2];   // t2z t3x t3y t3z
        const float4 p0 = {v0.x, v0.w, v1.z, v2.y};
        const float4 p1 = {v0.y, v1.x, v1.w, v2.z};
        const float4 p2 = {v0.z, v1.y, v2.x, v2.w};
        ((float4*)(xT + 0 * PLANE))[gid] = p0;
        ((float4*)(xT + 1 * PLANE))[gid] = p1;
        ((float4*)(xT + 2 * PLANE))[gid] = p2;
        return;
    }
    // ---- fold part ----
    const int jj = tid & 15;
    const int hs = tid >> 4;                 // 0..15
    const int j = blockIdx.x * 16 + jj;
    float mz0 = 0.f, mz1 = 0.f, mz2 = 0.f, cz = 0.f;
    float mh0 = 0.f, mh1 = 0.f, mh2 = 0.f, ch = 0.f;
#pragma unroll
    for (int i = 0; i < 16; ++i) {
        const int h = hs * 16 + i;
        const float wz = Wz[h * NH + j];
        const float wh = Wh[h * NH + j];
        const float p0 = Wp[h];
        const float p1 = Wp[NH + h];
        const float p2 = Wp[2 * NH + h];
        const float bb = bp[h];
        mz0 = fmaf(p0, wz, mz0); mz1 = fmaf(p1, wz, mz1); mz2 = fmaf(p2, wz, mz2);
        cz  = fmaf(bb, wz, cz);
        mh0 = fmaf(p0, wh, mh0); mh1 = fmaf(p1, wh, mh1); mh2 = fmaf(p2, wh, mh2);
        ch  = fmaf(bb, wh, ch);
    }
    __shared__ float red[256][9];
    red[tid][0] = mz0; red[tid][1] = mz1; red[tid][2] = mz2; red[tid][3] = cz;
    red[tid][4] = mh0; red[tid][5] = mh1; red[tid][6] = mh2; red[tid][7] = ch;
    __syncthreads();
    if (tid < 16) {
        float v[8];
#pragma unroll
        for (int k = 0; k < 8; ++k) {
            float a = 0.f;
#pragma unroll
            for (int g = 0; g < 16; ++g) a += red[g * 16 + tid][k];
            v[k] = a;
        }
        v[3] += bz[j];
        v[7] += bh[j];
        const float SZ = -1.4426950408889634f;   // -log2(e)
        const float SH = -2.8853900817779268f;   // -2*log2(e)
        float4* w4 = (float4*)(wsW + j * 8);
        w4[0] = make_float4(v[0] * SZ, v[1] * SZ, v[2] * SZ, v[3] * SZ);
        w4[1] = make_float4(v[4] * SH, v[5] * SH, v[6] * SH, v[7] * SH);
    }
}

// Gate math for 2 timesteps, 12 VALU + 6 trans:
//   q  = e1*(1+e2) = fma(e1,e2,e1)
//   den = (1+e1)(1+e2) = q + e2 + 1
//   a = q/den, b = (1-e2)/den  (two direct rcps; trans pipe has slack)
#define GATE2(XQ, U0, AV, BV)                                                   \
    {                                                                           \
        const float* xf_ = (const float*)(XQ);                                  \
        const f32x2 xx_ = *(const f32x2*)&xf_[2*(U0)];                          \
        const f32x2 xy_ = *(const f32x2*)&xf_[8 + 2*(U0)];                      \
        const f32x2 xz_ = *(const f32x2*)&xf_[16 + 2*(U0)];                     \
        const f32x2 s1_ = pkfma(xx_, wax, pkfma(xy_, way, pkfma(xz_, waz, waw)));\
        const f32x2 s2_ = pkfma(xx_, wbx, pkfma(xy_, wby, pkfma(xz_, wbz, wbw)));\
        f32x2 e1_, e2_;                                                         \
        e1_.x = fexp2(s1_.x); e1_.y = fexp2(s1_.y);                             \
        e2_.x = fexp2(s2_.x); e2_.y = fexp2(s2_.y);                             \
        const f32x2 q_  = pkfma(e1_, e2_, e1_);                                 \
        f32x2 den_ = q_ + e2_;                                                  \
        den_ = den_ + 1.f;                                                      \
        f32x2 rr_; rr_.x = frcp(den_.x); rr_.y = frcp(den_.y);                  \
        AV = q_ * rr_;                     /* a = 1-z    */                     \
        BV = (1.f - e2_) * rr_;            /* b = z*tanh */                     \
    }

// Load 8 timesteps (sub-chunk SC) from the 3 plane pointers.
#define LOAD8(XQ, SC)                                                           \
    {                                                                           \
        XQ[0] = p04[(SC) * 2];     XQ[1] = p04[(SC) * 2 + 1];                   \
        XQ[2] = p14[(SC) * 2];     XQ[3] = p14[(SC) * 2 + 1];                   \
        XQ[4] = p24[(SC) * 2];     XQ[5] = p24[(SC) * 2 + 1];                   \
    }

// ---------------------------------------------------------------------------
// Pass 1: per-(batch, segment) blocks (thread = channel). Segment composite
// (A, B): h_end = A*h_start + B. Segment 15's composite is never read -> skip.
// ---------------------------------------------------------------------------
__global__ __launch_bounds__(256, 8) void pass1_seg(
        const float* __restrict__ xT, const float* __restrict__ wsW,
        float* __restrict__ Aarr, float* __restrict__ Barr) {
    const int tid = threadIdx.x;
    const int b = blockIdx.x >> 4;           // NSEG = 16
    const int s = blockIdx.x & (NSEG - 1);
    if (s == NSEG - 1) return;               // last segment's composite unused

    const float4* wv = (const float4*)(wsW + tid * 8);
    const float4 wA4 = wv[0];
    const float4 wB4 = wv[1];
    const f32x2 wax = splat2(wA4.x), way = splat2(wA4.y), waz = splat2(wA4.z), waw = splat2(wA4.w);
    const f32x2 wbx = splat2(wB4.x), wby = splat2(wB4.y), wbz = splat2(wB4.z), wbw = splat2(wB4.w);

    const int base = b * NL + s * SEGLEN;    // block-uniform
    const float4* p04 = (const float4*)(xT + 0 * PLANE + base);
    const float4* p14 = (const float4*)(xT + 1 * PLANE + base);
    const float4* p24 = (const float4*)(xT + 2 * PLANE + base);

#define P1_BODY(XQ)                                                             \
    _Pragma("unroll")                                                           \
    for (int u0 = 0; u0 < 4; ++u0) {                                            \
        f32x2 av, bv;                                                           \
        GATE2(XQ, u0, av, bv);                                                  \
        Bacc = fmaf(av.x, Bacc, bv.x);                                          \
        Bacc = fmaf(av.y, Bacc, bv.y);                                          \
        Apk *= av;                                                              \
    }

    f32x2 Apk = { 1.f, 1.f };
    float Bacc = 0.f;
    float4 xa[6], xb[6];
    LOAD8(xa, 0);
    for (int c = 0; c < 8; ++c) {            // 16 timesteps per iter
        LOAD8(xb, 2 * c + 1);
        P1_BODY(xa);
        const int nxt = (c < 7) ? (2 * c + 2) : 0;
        LOAD8(xa, nxt);
        P1_BODY(xb);
    }
    const size_t o = ((size_t)b * NSEG + s) * NH + tid;
    Aarr[o] = Apk.x * Apk.y;
    Barr[o] = Bacc;
#undef P1_BODY
}

// ---------------------------------------------------------------------------
// Pass 3: per-(batch, segment) blocks. Prefix over earlier segments' (A,B)
// (loop bounded by s, uniform), then scaled recurrence g = a*g + wg*b.
// Pred-reduction over 256 channels via f16x2-packed LDS transpose per 32 t.
// ---------------------------------------------------------------------------
__global__ __launch_bounds__(256, 8) void pass3_pred(
        const float* __restrict__ xT, const float* __restrict__ wsW,
        const float* __restrict__ Wg, const float* __restrict__ bg,
        const float* __restrict__ Aarr, const float* __restrict__ Barr,
        float* __restrict__ out) {
    const int tid = threadIdx.x;
    const int b = blockIdx.x >> 4;
    const int s = blockIdx.x & (NSEG - 1);

    const float4* wv = (const float4*)(wsW + tid * 8);
    const float4 wA4 = wv[0];
    const float4 wB4 = wv[1];
    const f32x2 wax = splat2(wA4.x), way = splat2(wA4.y), waz = splat2(wA4.z), waw = splat2(wA4.w);
    const f32x2 wbx = splat2(wB4.x), wby = splat2(wB4.y), wbz = splat2(wB4.z), wbw = splat2(wB4.w);
    const float wg = Wg[tid];
    const f32x2 wgpk = splat2(wg);
    const float bgv = bg[0];

    // ---- segment-start state: prefix over earlier segments' (A,B) ----
    float h = 0.f;
    {
        const size_t pbase = (size_t)b * NSEG * NH + tid;
        for (int k0 = 0; k0 < s; k0 += 8) {      // s uniform per block
            float Ak[8], Bk[8];
#pragma unroll
            for (int k = 0; k < 8; ++k) {
                const int kk = k0 + k;
                const bool u = kk < s;           // uniform predicate
                Ak[k] = u ? Aarr[pbase + (size_t)kk * NH] : 1.f;
                Bk[k] = u ? Barr[pbase + (size_t)kk * NH] : 0.f;
            }
#pragma unroll
            for (int k = 0; k < 8; ++k) h = fmaf(Ak[k], h, Bk[k]);
        }
    }
    float g = h * wg;                        // scaled state: pred_t = g_{t-1}

    const int base = b * NL + s * SEGLEN;
    const float4* p04 = (const float4*)(xT + 0 * PLANE + base);
    const float4* p14 = (const float4*)(xT + 1 * PLANE + base);
    const float4* p24 = (const float4*)(xT + 2 * PLANE + base);

    __shared__ unsigned int pbuf[NH * PBPITCH];   // f16x2 t-pairs, 17408 B
    __shared__ unsigned int part2[16 * PBPITCH];  // [grp][q] f16x2

    const int q   = tid & 15;                // stage2: t-pair index (0..15)
    const int grp = tid >> 4;                // stage2: channel group (16 ch)

#define P3_BODY(XQ, Q0)                                                         \
    _Pragma("unroll")                                                           \
    for (int u0 = 0; u0 < 4; ++u0) {                                            \
        f32x2 av, bv;                                                           \
        GATE2(XQ, u0, av, bv);                                                  \
        const f32x2 bw = bv * wgpk;                                             \
        const float p0_ = g;                 /* pred uses state BEFORE update */\
        g = fmaf(av.x, g, bw.x);                                                \
        const float p1_ = g;                                                    \
        g = fmaf(av.y, g, bw.y);                                                \
        U32H2 pk_; pk_.h = __builtin_amdgcn_cvt_pkrtz(p0_, p1_);                \
        pbuf[tid * PBPITCH + (Q0) + u0] = pk_.u;                                \
    }

    float4 xa[6], xb[6];
    LOAD8(xa, 0);
    for (int c2 = 0; c2 < 4; ++c2) {         // 32 timesteps per iter
        LOAD8(xb, 4 * c2 + 1);
        P3_BODY(xa, 0);
        LOAD8(xa, 4 * c2 + 2);
        P3_BODY(xb, 4);
        LOAD8(xb, 4 * c2 + 3);
        P3_BODY(xa, 8);
        {
            const int nxt = (c2 < 3) ? (4 * c2 + 4) : 0;
            LOAD8(xa, nxt);
        }
        P3_BODY(xb, 12);
        __syncthreads();
        // stage 2: thread (grp,q) sums 16 channels for t-pair q (pk_add_f16)
        {
            f16x2 acc2 = (f16x2)0.f;
#pragma unroll
            for (int j = 0; j < 16; ++j) {
                U32H2 rd; rd.u = pbuf[(grp * 16 + j) * PBPITCH + q];
                acc2 += rd.h;
            }
            U32H2 wr; wr.h = acc2;
            part2[grp * PBPITCH + q] = wr.u;
        }
        __syncthreads();
        // stage 3: 16 threads sum 16 group-partials for their t-pair + bias
        if (tid < 16) {
            f16x2 a3 = (f16x2)0.f;
#pragma unroll
            for (int g2 = 0; g2 < 16; ++g2) {
                U32H2 rd; rd.u = part2[g2 * PBPITCH + tid];
                a3 += rd.h;
            }
            float2 o2;
            o2.x = (float)a3.x + bgv;
            o2.y = (float)a3.y + bgv;
            *(float2*)&out[(size_t)b * NL + (size_t)s * SEGLEN + c2 * RCHUNK + 2 * tid] = o2;
        }
    }
#undef P3_BODY
}

// ---------------------------------------------------------------------------
// Fallback (ws too small): monolithic scan, 128 blocks x 256 thr (orig x).
// Weights folded by a tiny standalone fold pass (prep kernel's fold half).
// ---------------------------------------------------------------------------
__global__ __launch_bounds__(256) void scan_kernel_nows(
        const float* __restrict__ x, const float* __restrict__ wsW,
        const float* __restrict__ Wg, const float* __restrict__ bg,
        float* __restrict__ out) {
    const int tid  = threadIdx.x;
    const int lane = tid & 63;
    const int wid  = tid >> 6;
    const int b = blockIdx.x;

    const float4* wv = (const float4*)(wsW + tid * 8);
    const float4 wA = wv[0];
    const float4 wB = wv[1];
    const float  wg = Wg[tid];
    const float  bgv = bg[0];

    const float* xb = x + (size_t)b * (NL * 3);

    __shared__ float4 xbuf[2][CHUNK];
    __shared__ float  predbuf[2][4][CHUNK];
    float* xbf = (float*)xbuf;

    const int sw = tid;
    const int sidx = (sw / 3) * 4 + (sw % 3);

    if (tid < WORDS) xbf[sidx] = xb[sw];
    __syncthreads();

    float h = 0.f;
    for (int c = 0; c < NCHUNK; ++c) {
        const int cur = c & 1;
        float nv = 0.f;
        if (tid < WORDS && c + 1 < NCHUNK) nv = xb[(c + 1) * WORDS + sw];

        float p[CHUNK];
        const float4* xc = xbuf[cur];
#pragma unroll
        for (int t = 0; t < CHUNK; ++t) {
            const float4 xv = xc[t];
            const float e1 = fexp2(fmaf(xv.x, wA.x, fmaf(xv.y, wA.y, fmaf(xv.z, wA.z, wA.w))));
            const float e2 = fexp2(fmaf(xv.x, wB.x, fmaf(xv.y, wB.y, fmaf(xv.z, wB.z, wB.w))));
            const float d2 = 1.f + e2;
            const float e1d2 = e1 * d2;
            const float r  = frcp(e1d2 + d2);
            p[t] = h * wg;
            h = fmaf(e1d2 * r, h, (1.f - e2) * r);
        }
#pragma unroll
        for (int t = 0; t < CHUNK; ++t) {
            float v = p[t];
            v += __shfl_xor(v, 1, 64);
            v += __shfl_xor(v, 2, 64);
            v += __shfl_xor(v, 4, 64);
            v += __shfl_xor(v, 8, 64);
            v += __shfl_xor(v, 16, 64);
            v += __shfl_xor(v, 32, 64);
            p[t] = v;
        }
        if (lane == 0) {
            float4* dpr = (float4*)&predbuf[cur][wid][0];
#pragma unroll
            for (int j2 = 0; j2 < CHUNK / 4; ++j2)
                dpr[j2] = make_float4(p[4*j2], p[4*j2+1], p[4*j2+2], p[4*j2+3]);
        }
        if (tid < WORDS && c + 1 < NCHUNK) xbf[(cur ^ 1) * CHUNK * 4 + sidx] = nv;
        __syncthreads();
        if (tid < CHUNK) {
            const float ssum = predbuf[cur][0][tid] + predbuf[cur][1][tid]
                             + predbuf[cur][2][tid] + predbuf[cur][3][tid];
            out[(size_t)b * NL + c * CHUNK + tid] = ssum + bgv;
        }
    }
}

extern "C" void kernel_launch(void* const* d_in, const int* in_sizes, int n_in,
                              void* d_out, int out_size, void* d_ws, size_t ws_size,
                              hipStream_t stream) {
    const float* x  = (const float*)d_in[0];
    const float* Wp = (const float*)d_in[1];
    const float* bp = (const float*)d_in[2];
    const float* Wz = (const float*)d_in[3];
    const float* bz = (const float*)d_in[4];
    const float* Wh = (const float*)d_in[5];
    const float* bh = (const float*)d_in[6];
    const float* Wg = (const float*)d_in[7];
    const float* bg = (const float*)d_in[8];
    float* out = (float*)d_out;

    float* wsW = (float*)d_ws;                       // 8 KB folded weights
    float* Aarr = wsW + 8 * NH;                      // 2 MB
    float* Barr = Aarr + (size_t)NB * NSEG * NH;     // 2 MB
    float* xTp  = Barr + (size_t)NB * NSEG * NH;     // 3 MB planes

    const size_t need = ((size_t)(8 * NH) + 2 * (size_t)NB * NSEG * NH
                        + 3 * (size_t)PLANE) * sizeof(float);

    if (ws_size >= need) {
        prep_kernel<<<16 + PLANE / 4 / 256, 256, 0, stream>>>(
            x, xTp, Wp, bp, Wz, bz, Wh, bh, wsW);
        pass1_seg<<<NB * NSEG, 256, 0, stream>>>(xTp, wsW, Aarr, Barr);
        pass3_pred<<<NB * NSEG, 256, 0, stream>>>(xTp, wsW, Wg, bg, Aarr, Barr, out);
    } else {
        prep_kernel<<<16, 256, 0, stream>>>(
            x, (float*)nullptr, Wp, bp, Wz, bz, Wh, bh, wsW);  // fold-only
        scan_kernel_nows<<<NB, 256, 0, stream>>>(x, wsW, Wg, bg, out);
    }
}